// Round 6
// baseline (632.856 us; speedup 1.0000x reference)
//
#include <hip/hip_runtime.h>
#include <hip/hip_bf16.h>
#include <cstdint>

#define D_DIM 768
#define BM 128
#define BN 256
#define BK 128                  // K-tile; 2 ks-steps of the K=64 MFMA; 6 tiles
#define KCH (D_DIM / 64)        // 12 A k-chunks
#define RBLK 24576              // A swizzled: 12 * 2048 B per 32-row block

typedef int   intx8    __attribute__((ext_vector_type(8)));
typedef float floatx16 __attribute__((ext_vector_type(16)));

#define SCALE_ONE 0x7F7F7F7F  // E8M0 127 = 2^0 in every byte

// ---- helpers ----------------------------------------------------------------

__device__ inline void lds_load16(const void* g, void* lds) {
  __builtin_amdgcn_global_load_lds(
      (const __attribute__((address_space(1))) unsigned int*)g,
      (__attribute__((address_space(3))) unsigned int*)lds,
      16, 0, 0);
}

__device__ inline intx8 ldfrag2(const unsigned char* p, int o0, int o1) {
  intx8 r;
  *(int4*)&r       = *(const int4*)(p + o0);
  *((int4*)&r + 1) = *(const int4*)(p + o1);
  return r;
}

// ---- kernel 1: row L2 norm + fp8 cast. A rows -> operand-swizzled blocks ----
// (layout verified absmax=0 in R5); B rows -> linear fp8 (R4 path).

__global__ __launch_bounds__(256) void norm_cast_kernel(
    const float* __restrict__ EX, const float* __restrict__ EY,
    unsigned int* __restrict__ XO, unsigned int* __restrict__ YO, int Nx) {
  int row = blockIdx.x * 4 + (threadIdx.x >> 6);
  int lane = threadIdx.x & 63;
  bool isA = row < Nx;
  const float* X = isA ? EX : EY;
  int r = isA ? row : (row - Nx);
  const float4* xr = (const float4*)(X + (size_t)r * D_DIM);
  float4 a = xr[lane];
  float4 b = xr[lane + 64];
  float4 c = xr[lane + 128];
  float ss = a.x*a.x + a.y*a.y + a.z*a.z + a.w*a.w
           + b.x*b.x + b.y*b.y + b.z*b.z + b.w*b.w
           + c.x*c.x + c.y*c.y + c.z*c.z + c.w*c.w;
  #pragma unroll
  for (int off = 32; off > 0; off >>= 1) ss += __shfl_xor(ss, off, 64);
  float s = 1.0f / fmaxf(sqrtf(ss), 1e-8f);
  int d0, d1, d2;
  d0 = __builtin_amdgcn_cvt_pk_fp8_f32(a.x * s, a.y * s, 0, false);
  d0 = __builtin_amdgcn_cvt_pk_fp8_f32(a.z * s, a.w * s, d0, true);
  d1 = __builtin_amdgcn_cvt_pk_fp8_f32(b.x * s, b.y * s, 0, false);
  d1 = __builtin_amdgcn_cvt_pk_fp8_f32(b.z * s, b.w * s, d1, true);
  d2 = __builtin_amdgcn_cvt_pk_fp8_f32(c.x * s, c.y * s, 0, false);
  d2 = __builtin_amdgcn_cvt_pk_fp8_f32(c.z * s, c.w * s, d2, true);
  if (isA) {
    // swizzled scatter: k=4*lane -> kc=lane>>4, chunk=(lane>>2)&1, h=(lane>>3)&1
    unsigned int* dst = (unsigned int*)((char*)XO + (size_t)(r >> 5) * RBLK);
    int off = ((lane >> 4) * 2048) + (((lane >> 2) & 1) * 1024)
            + ((((lane >> 3) & 1) * 32 + (r & 31)) * 16) + ((lane & 3) * 4);
    dst[off >> 2]           = (unsigned int)d0;
    dst[(off + 8192) >> 2]  = (unsigned int)d1;   // kc += 4
    dst[(off + 16384) >> 2] = (unsigned int)d2;   // kc += 8
  } else {
    unsigned int* yr = YO + (size_t)r * (D_DIM / 4);
    yr[lane]       = (unsigned int)d0;
    yr[lane + 64]  = (unsigned int)d1;
    yr[lane + 128] = (unsigned int)d2;
  }
}

// ---- kernel 2: MX-fp8 MFMA GEMM (S = A . B^T) fused with per-row max --------
// Block 128x256, 4 waves (2x2), wave tile 64x128 = 2x4 of 32x32x64 mfma_scale.
// A: direct from global, pre-swizzled operand blocks (no staging, L2-resident,
//    reused by all 64 y-blocks). B: LDS, DOUBLE-buffered — stage tile kt+1
//    before computing tile kt, so the vmcnt drain at the single per-tile
//    barrier is hidden behind ~16 mfma of compute. R4 lesson: single-buffered
//    staging exposes full deposit latency per tile (conflict counter = exactly
//    32 cyc x deposit instrs; MfmaUtil capped at 31%). R5 lesson: no LDS at
//    all loses reuse (FETCH 767 MB) and frag-dbuf spills (WRITE 1.3 GB).

__global__ __launch_bounds__(256, 2) void gemm_max_kernel(
    const unsigned char* __restrict__ A,   // A_sw [Nx/32][12][2048]
    const unsigned char* __restrict__ B,   // eyn  [Ny][768] fp8 row-major
    float* __restrict__ partial,           // [ncb][Nx]
    int Nx) {
  __shared__ unsigned char Bs[2][BN * BK];  // 2 x 32 KB
  __shared__ float red[2][BM];

  const int tid  = threadIdx.x;
  const int wave = tid >> 6;
  const int lane = tid & 63;
  const int wm = wave >> 1;        // 0..1: row half (64 rows)
  const int wn = wave & 1;         // 0..1: col half (128 cols)
  const int l31 = lane & 31;
  const int h   = lane >> 5;
  const int skey = l31 & 7;        // B read-side swizzle key

  floatx16 acc[2][4];
  #pragma unroll
  for (int mt = 0; mt < 2; ++mt)
    #pragma unroll
    for (int nt = 0; nt < 4; ++nt)
      acc[mt][nt] = (floatx16)(0.f);

  // A fragment base pointers (lane-strided within 2 KB operand blocks)
  const unsigned char* aB[2];
  #pragma unroll
  for (int mt = 0; mt < 2; ++mt)
    aB[mt] = A + (size_t)(blockIdx.x * 4 + wm * 2 + mt) * RBLK + lane * 16;

  // B staging: wave stages 64 rows (8 instrs x 1 KB); deposit lane -> row
  // lane>>3, phys chunk lane&7 -> global chunk (lane&7)^((lane>>3)&7).
  const int srow = lane >> 3;
  const int sj = (lane & 7) ^ (srow & 7);
  const unsigned char* gB =
      B + (size_t)(blockIdx.y * BN + wave * 64 + srow) * D_DIM + sj * 16;
  const size_t g8 = (size_t)8 * D_DIM;
  unsigned char* lB[2] = { Bs[0] + (size_t)(wave * 64) * BK,
                           Bs[1] + (size_t)(wave * 64) * BK };

  // B fragment row bases per buffer
  const unsigned char* pB[2][4];
  #pragma unroll
  for (int bufi = 0; bufi < 2; ++bufi)
    #pragma unroll
    for (int nt = 0; nt < 4; ++nt)
      pB[bufi][nt] = Bs[bufi] + (size_t)(wn * 128 + nt * 32 + l31) * BK;

  // prologue: stage tile 0 into buf 0
  #pragma unroll
  for (int i = 0; i < 8; ++i)
    lds_load16(gB + i * g8, lB[0] + i * 1024);
  __syncthreads();

  #pragma unroll
  for (int kt = 0; kt < D_DIM / BK; ++kt) {
    const int cur = kt & 1;
    if (kt + 1 < D_DIM / BK) {        // stage next tile into the other buffer
      #pragma unroll
      for (int i = 0; i < 8; ++i)
        lds_load16(gB + (kt + 1) * BK + i * g8, lB[cur ^ 1] + i * 1024);
    }
    #pragma unroll
    for (int ks = 0; ks < 2; ++ks) {  // two K=64 MFMA steps
      const int kc = kt * 2 + ks;     // A k-chunk
      const int c0 = ks * 4 + 2 * h;  // B logical 16B chunk pair {c0, c0+1}
      const int o0 = (c0 ^ skey) * 16;
      const int o1 = ((c0 + 1) ^ skey) * 16;
      intx8 a0, a1, b;
      { const unsigned char* p = aB[0] + kc * 2048;
        *(int4*)&a0 = *(const int4*)p; *((int4*)&a0 + 1) = *(const int4*)(p + 1024); }
      { const unsigned char* p = aB[1] + kc * 2048;
        *(int4*)&a1 = *(const int4*)p; *((int4*)&a1 + 1) = *(const int4*)(p + 1024); }
      b = ldfrag2(pB[cur][0], o0, o1);
      acc[0][0] = __builtin_amdgcn_mfma_scale_f32_32x32x64_f8f6f4(
          a0, b, acc[0][0], 0, 0, 0, SCALE_ONE, 0, SCALE_ONE);
      acc[1][0] = __builtin_amdgcn_mfma_scale_f32_32x32x64_f8f6f4(
          a1, b, acc[1][0], 0, 0, 0, SCALE_ONE, 0, SCALE_ONE);
      b = ldfrag2(pB[cur][1], o0, o1);
      acc[0][1] = __builtin_amdgcn_mfma_scale_f32_32x32x64_f8f6f4(
          a0, b, acc[0][1], 0, 0, 0, SCALE_ONE, 0, SCALE_ONE);
      acc[1][1] = __builtin_amdgcn_mfma_scale_f32_32x32x64_f8f6f4(
          a1, b, acc[1][1], 0, 0, 0, SCALE_ONE, 0, SCALE_ONE);
      b = ldfrag2(pB[cur][2], o0, o1);
      acc[0][2] = __builtin_amdgcn_mfma_scale_f32_32x32x64_f8f6f4(
          a0, b, acc[0][2], 0, 0, 0, SCALE_ONE, 0, SCALE_ONE);
      acc[1][2] = __builtin_amdgcn_mfma_scale_f32_32x32x64_f8f6f4(
          a1, b, acc[1][2], 0, 0, 0, SCALE_ONE, 0, SCALE_ONE);
      b = ldfrag2(pB[cur][3], o0, o1);
      acc[0][3] = __builtin_amdgcn_mfma_scale_f32_32x32x64_f8f6f4(
          a0, b, acc[0][3], 0, 0, 0, SCALE_ONE, 0, SCALE_ONE);
      acc[1][3] = __builtin_amdgcn_mfma_scale_f32_32x32x64_f8f6f4(
          a1, b, acc[1][3], 0, 0, 0, SCALE_ONE, 0, SCALE_ONE);
    }
    __syncthreads();  // buf consumed; deposits (issued pre-compute) drained
  }

  // epilogue: per-row max over this block's 256 columns.
  // C/D (32x32): col = l31 (+nt*32 + wn*128), row = (reg&3)+8*(reg>>2)+4*h (+mt*32+wm*64)
  #pragma unroll
  for (int mt = 0; mt < 2; ++mt) {
    #pragma unroll
    for (int reg = 0; reg < 16; ++reg) {
      float v = fmaxf(fmaxf(acc[mt][0][reg], acc[mt][1][reg]),
                      fmaxf(acc[mt][2][reg], acc[mt][3][reg]));
      #pragma unroll
      for (int off = 1; off < 32; off <<= 1)
        v = fmaxf(v, __shfl_xor(v, off, 64));
      if (l31 == 0) {
        int r = wm * 64 + mt * 32 + (reg & 3) + 8 * (reg >> 2) + 4 * h;
        red[wn][r] = v;
      }
    }
  }
  __syncthreads();
  if (tid < BM) {
    float m = fmaxf(red[0][tid], red[1][tid]);
    partial[(size_t)blockIdx.y * Nx + blockIdx.x * BM + tid] = m;
  }
}

// ---- kernel 3: row max over column blocks + halfnormal transform + block sum

__global__ __launch_bounds__(256) void rowmax_kernel(
    const float* __restrict__ partial, float* __restrict__ bsum, int Nx, int ncb) {
  __shared__ float sdata[4];
  int r = blockIdx.x * blockDim.x + threadIdx.x;
  float m = -1e30f;
  for (int cb = 0; cb < ncb; ++cb)
    m = fmaxf(m, partial[(size_t)cb * Nx + r]);
  float x = 1.0f - m;
  const float logc = -0.22579135264472744f;  // 0.5*log(2/pi), sigma=1
  float l = logc - 0.5f * x * x;
  float t = -__expf(l) * l;
  #pragma unroll
  for (int off = 32; off > 0; off >>= 1) t += __shfl_xor(t, off, 64);
  int wave = threadIdx.x >> 6;
  int lane = threadIdx.x & 63;
  if (lane == 0) sdata[wave] = t;
  __syncthreads();
  if (threadIdx.x == 0)
    bsum[blockIdx.x] = sdata[0] + sdata[1] + sdata[2] + sdata[3];
}

// ---- kernel 4: final sum of block partials -> out[0], out[1] ----------------

__global__ __launch_bounds__(64) void final_kernel(
    const float* __restrict__ bsum, float* __restrict__ out, int nb) {
  int lane = threadIdx.x;
  float s = (lane < nb) ? bsum[lane] : 0.f;
  #pragma unroll
  for (int off = 32; off > 0; off >>= 1) s += __shfl_xor(s, off, 64);
  if (lane == 0) { out[0] = s; out[1] = s; }
}

// ---- launch -----------------------------------------------------------------

extern "C" void kernel_launch(void* const* d_in, const int* in_sizes, int n_in,
                              void* d_out, int out_size, void* d_ws, size_t ws_size,
                              hipStream_t stream) {
  const float* ex = (const float*)d_in[0];
  const float* ey = (const float*)d_in[1];
  const int Nx = in_sizes[0] / D_DIM;   // 8192
  const int Ny = in_sizes[1] / D_DIM;   // 16384
  const int ncb = Ny / BN;              // 64

  char* ws = (char*)d_ws;
  unsigned char* exn = (unsigned char*)ws;                 // A swizzled: Nx/32 * 24576
  unsigned char* eyn = exn + (size_t)(Nx / 32) * RBLK;     // B linear: Ny*768
  float* partial = (float*)(eyn + (size_t)Ny * D_DIM);     // ncb*Nx f32
  float* bsum    = partial + (size_t)ncb * Nx;             // 32 f32

  norm_cast_kernel<<<(Nx + Ny) / 4, 256, 0, stream>>>(
      ex, ey, (unsigned int*)exn, (unsigned int*)eyn, Nx);
  gemm_max_kernel<<<dim3(Nx / BM, Ny / BN), 256, 0, stream>>>(exn, eyn, partial, Nx);
  rowmax_kernel<<<Nx / 256, 256, 0, stream>>>(partial, bsum, Nx, ncb);
  final_kernel<<<1, 64, 0, stream>>>(bsum, (float*)d_out, Nx / 256);
}